// Round 1
// baseline (72.426 us; speedup 1.0000x reference)
//
#include <hip/hip_runtime.h>
#include <stdint.h>

// SpikingKWTA collapses analytically (see analysis):
//   * With potentials_init == 0, every potential is EXACTLY 0.0f after every
//     step (0*decay=0; 0+1=1.0 >= thr=1.0 -> spike -> 1.0-1.0=0.0 exact).
//   * => spk == bincount(token_ids); final pot == 0 everywhere.
//   * => values = spk*1e6 exactly; top_k ties resolved by lowest index
//     (lax.top_k stable tie-break). Encode rank as u64 key
//     (count<<32)|(~v) so max-reduce == (count desc, index asc).
//   * L>=1 => at least one spike => the "all ones" fallback never fires.
// Output: gains[v] = count>0 ? 0.6 : 1.0; gains[top5] = 1.5.

#define THREADS 256
#define K_WIN 5

__global__ void zero_counts_kernel(uint32_t* __restrict__ counts, int n4) {
    int i = blockIdx.x * blockDim.x + threadIdx.x;
    int4* p = reinterpret_cast<int4*>(counts);
    if (i < n4) p[i] = make_int4(0, 0, 0, 0);
}

__global__ void hist_kernel(const int* __restrict__ ids,
                            uint32_t* __restrict__ counts, int L) {
    int i = blockIdx.x * blockDim.x + threadIdx.x;
    if (i < L) atomicAdd(&counts[ids[i]], 1u);
}

// One thread per vocab entry: write gains default/active, and per-block top-5
// candidate keys via 5 rounds of shared-memory max-reduction.
__global__ void gains_block_top5_kernel(const uint32_t* __restrict__ counts,
                                        float* __restrict__ gains,
                                        unsigned long long* __restrict__ cand,
                                        int V) {
    int v = blockIdx.x * blockDim.x + threadIdx.x;
    unsigned long long key = 0ull;  // invalid (never produced for v < V)
    if (v < V) {
        uint32_t c = counts[v];
        gains[v] = c ? 0.6f : 1.0f;
        key = ((unsigned long long)c << 32) |
              (unsigned long long)(0xFFFFFFFFu - (uint32_t)v);
    }
    __shared__ unsigned long long s[THREADS];
    for (int it = 0; it < K_WIN; ++it) {
        s[threadIdx.x] = key;
        __syncthreads();
        for (int off = THREADS / 2; off > 0; off >>= 1) {
            if (threadIdx.x < off) {
                unsigned long long o = s[threadIdx.x + off];
                if (o > s[threadIdx.x]) s[threadIdx.x] = o;
            }
            __syncthreads();
        }
        unsigned long long w = s[0];
        __syncthreads();
        if (key == w) key = 0ull;  // winner retires (keys are unique per v)
        if (threadIdx.x == 0) cand[blockIdx.x * K_WIN + it] = w;
    }
}

// Single block: global top-5 over all block candidates, then 5 fixup stores.
__global__ void final_top5_kernel(const unsigned long long* __restrict__ cand,
                                  float* __restrict__ gains, int ncand) {
    unsigned long long loc[K_WIN] = {0ull, 0ull, 0ull, 0ull, 0ull};
    for (int i = threadIdx.x; i < ncand; i += blockDim.x) {
        unsigned long long k = cand[i];
        if (k > loc[K_WIN - 1]) {
            loc[K_WIN - 1] = k;
            for (int j = K_WIN - 1; j > 0 && loc[j] > loc[j - 1]; --j) {
                unsigned long long t = loc[j]; loc[j] = loc[j - 1]; loc[j - 1] = t;
            }
        }
    }
    __shared__ unsigned long long s[THREADS];
    __shared__ unsigned long long winners[K_WIN];
    for (int it = 0; it < K_WIN; ++it) {
        s[threadIdx.x] = loc[0];
        __syncthreads();
        for (int off = THREADS / 2; off > 0; off >>= 1) {
            if (threadIdx.x < off) {
                unsigned long long o = s[threadIdx.x + off];
                if (o > s[threadIdx.x]) s[threadIdx.x] = o;
            }
            __syncthreads();
        }
        unsigned long long w = s[0];
        __syncthreads();
        if (loc[0] == w) {  // my best won: shift my local list left
            for (int j = 0; j < K_WIN - 1; ++j) loc[j] = loc[j + 1];
            loc[K_WIN - 1] = 0ull;
        }
        if (threadIdx.x == 0) winners[it] = w;
        __syncthreads();
    }
    if (threadIdx.x < K_WIN) {
        unsigned long long w = winners[threadIdx.x];
        uint32_t idx = 0xFFFFFFFFu - (uint32_t)(w & 0xFFFFFFFFull);
        // Reference sets gains[topk_idx] = 1.5 unconditionally (even count==0),
        // and our key order matches lax.top_k exactly, so no guard.
        gains[idx] = 1.5f;
    }
}

extern "C" void kernel_launch(void* const* d_in, const int* in_sizes, int n_in,
                              void* d_out, int out_size, void* d_ws, size_t ws_size,
                              hipStream_t stream) {
    const int* ids = (const int*)d_in[0];    // token_ids (int32 per harness)
    const int L = in_sizes[0];               // 4096
    const int V = out_size;                  // 131072 (== vocab_size)
    float* gains = (float*)d_out;

    // ws layout: [counts: V * u32][cand: nblkV * 5 * u64]
    uint32_t* counts = (uint32_t*)d_ws;
    const int nblkV = (V + THREADS - 1) / THREADS;  // 512
    unsigned long long* cand =
        (unsigned long long*)((char*)d_ws + (size_t)V * sizeof(uint32_t));

    const int n4 = V / 4;  // V = 131072 is a multiple of 4
    zero_counts_kernel<<<(n4 + THREADS - 1) / THREADS, THREADS, 0, stream>>>(counts, n4);
    hist_kernel<<<(L + THREADS - 1) / THREADS, THREADS, 0, stream>>>(ids, counts, L);
    gains_block_top5_kernel<<<nblkV, THREADS, 0, stream>>>(counts, gains, cand, V);
    final_top5_kernel<<<1, THREADS, 0, stream>>>(cand, gains, nblkV * K_WIN);
}